// Round 1
// baseline (4200.515 us; speedup 1.0000x reference)
//
#include <hip/hip_runtime.h>
#include <hip/hip_bf16.h>
#include <math.h>

#define NN     8000
#define BATCH  4
#define SEQ    2000
#define DTR    64
#define NHTR   4
#define DHD    16
#define FFD    2048
#define TOUTD  16
#define HIDD   512
#define NHEADS 6
#define HCD    512
#define GIND   514
#define GOUT   3072
#define NEDGE  32000
#define ELOOP  40000   /* NEDGE + NN */

#define CDIV(a,b) (((a)+(b)-1)/(b))

__device__ __forceinline__ float selu_f(float x){
  const float a = 1.6732632423543772848f;
  const float s = 1.0507009873554805f;
  return x > 0.f ? s * x : s * a * (__expf(x) - 1.f);
}

// ---------------------------------------------------------------------------
// Generic C[M,N] = act(A[M,K] @ W[N,K]^T + bias). fp32, 64x64 tile, BK=16.
// ---------------------------------------------------------------------------
template<int ACT>  // 0=none 1=relu 2=selu
__global__ __launch_bounds__(256) void k_gemm(const float* __restrict__ A,
    const float* __restrict__ W, const float* __restrict__ bias,
    float* __restrict__ C, int M, int N, int K)
{
  __shared__ float As[16][68];
  __shared__ float Ws[16][68];
  const int tid = threadIdx.x;
  const int bm = blockIdx.y * 64, bn = blockIdx.x * 64;
  const int tx = tid & 15, ty = tid >> 4;
  float acc[4][4] = {};
  for (int k0 = 0; k0 < K; k0 += 16){
    #pragma unroll
    for (int i = 0; i < 4; ++i){
      int el = tid + (i << 8);          // 0..1023
      int kk = el & 15, r = el >> 4;    // 16 k  x 64 rows
      int gk = k0 + kk;
      int gm = bm + r;
      As[kk][r] = (gm < M && gk < K) ? A[(size_t)gm * K + gk] : 0.f;
      int gn = bn + r;
      Ws[kk][r] = (gn < N && gk < K) ? W[(size_t)gn * K + gk] : 0.f;
    }
    __syncthreads();
    #pragma unroll
    for (int kk = 0; kk < 16; ++kk){
      float av[4], wv[4];
      #pragma unroll
      for (int i = 0; i < 4; ++i) av[i] = As[kk][ty*4+i];
      #pragma unroll
      for (int j = 0; j < 4; ++j) wv[j] = Ws[kk][tx*4+j];
      #pragma unroll
      for (int i = 0; i < 4; ++i)
        #pragma unroll
        for (int j = 0; j < 4; ++j) acc[i][j] = fmaf(av[i], wv[j], acc[i][j]);
    }
    __syncthreads();
  }
  #pragma unroll
  for (int i = 0; i < 4; ++i){
    int gm = bm + ty*4 + i;
    if (gm >= M) continue;
    #pragma unroll
    for (int j = 0; j < 4; ++j){
      int gn = bn + tx*4 + j;
      if (gn >= N) continue;
      float v = acc[i][j] + bias[gn];
      if (ACT == 1) v = fmaxf(v, 0.f);
      if (ACT == 2) v = selu_f(v);
      C[(size_t)gm * N + gn] = v;
    }
  }
}

// ---------------------------------------------------------------------------
// h[n,d] = mesh[n,0:4] . embed_w[d,0:4] + embed_b[d]
// ---------------------------------------------------------------------------
__global__ void k_embed(const float* __restrict__ mesh,
                        const float* __restrict__ w, const float* __restrict__ b,
                        float* __restrict__ h)
{
  int i = blockIdx.x * blockDim.x + threadIdx.x;
  if (i >= NN * DTR) return;
  int n = i >> 6, d = i & 63;
  const float* mr = mesh + n * 4;
  const float* wr = w + d * 4;
  h[i] = fmaf(mr[0], wr[0], fmaf(mr[1], wr[1], fmaf(mr[2], wr[2], mr[3]*wr[3]))) + b[d];
}

// ---------------------------------------------------------------------------
// attention: thread per query, flash-style over LDS K/V tiles of 128 keys
// grid (CDIV(SEQ,128), BATCH, NHTR), block 128
// ---------------------------------------------------------------------------
__global__ __launch_bounds__(128) void k_attn(const float* __restrict__ qkv,
                                              float* __restrict__ o)
{
  __shared__ float Ks[128][DHD];
  __shared__ float Vs[128][DHD];
  const int q = blockIdx.x * 128 + threadIdx.x;
  const int b = blockIdx.y, h = blockIdx.z;
  const bool valid = q < SEQ;
  float qv[DHD];
  if (valid){
    #pragma unroll
    for (int d = 0; d < DHD; ++d)
      qv[d] = qkv[((size_t)(b*SEQ + q))*192 + h*DHD + d];
  }
  float m = -1e30f, l = 0.f, acc[DHD] = {};
  for (int kt = 0; kt < SEQ; kt += 128){
    int cnt = min(128, SEQ - kt);
    __syncthreads();
    for (int el = threadIdx.x; el < cnt * DHD; el += 128){
      int r = el >> 4, d = el & 15;
      size_t base = ((size_t)(b*SEQ + kt + r))*192 + h*DHD + d;
      Ks[r][d] = qkv[base + 64];
      Vs[r][d] = qkv[base + 128];
    }
    __syncthreads();
    if (valid){
      for (int r = 0; r < cnt; ++r){
        float s = 0.f;
        #pragma unroll
        for (int d = 0; d < DHD; ++d) s = fmaf(qv[d], Ks[r][d], s);
        s *= 0.25f;
        float mn = fmaxf(m, s);
        float cc = __expf(m - mn), p = __expf(s - mn);
        l = l * cc + p;
        #pragma unroll
        for (int d = 0; d < DHD; ++d) acc[d] = fmaf(acc[d], cc, p * Vs[r][d]);
        m = mn;
      }
    }
  }
  if (valid){
    float inv = 1.f / l;
    #pragma unroll
    for (int d = 0; d < DHD; ++d)
      o[((size_t)(b*SEQ + q))*64 + h*DHD + d] = acc[d] * inv;
  }
}

// ---------------------------------------------------------------------------
// out = LN(x + y) * g + b over rows of 64; one wave per row, block = 4 rows
// ---------------------------------------------------------------------------
__global__ __launch_bounds__(256) void k_addln(const float* __restrict__ x,
    const float* __restrict__ y, const float* __restrict__ g,
    const float* __restrict__ b, float* __restrict__ out)
{
  int row = blockIdx.x * 4 + (threadIdx.x >> 6);
  int lane = threadIdx.x & 63;
  if (row >= NN) return;
  float v = x[(size_t)row*64 + lane] + y[(size_t)row*64 + lane];
  float s1 = v, s2 = v * v;
  #pragma unroll
  for (int o = 32; o; o >>= 1){ s1 += __shfl_xor(s1, o); s2 += __shfl_xor(s2, o); }
  float mean = s1 * (1.f/64.f);
  float var  = s2 * (1.f/64.f) - mean * mean;
  float r = rsqrtf(var + 1e-5f);
  out[(size_t)row*64 + lane] = (v - mean) * r * g[lane] + b[lane];
}

__global__ void k_concat_feats(const float* __restrict__ x,
                               const float* __restrict__ tout,
                               float* __restrict__ feats)
{
  int i = blockIdx.x * blockDim.x + threadIdx.x;
  if (i >= NN * 21) return;
  int n = i / 21, c = i - 21*n;
  feats[i] = (c < 5) ? x[(size_t)n*7 + 2 + c] : tout[(size_t)n*16 + c - 5];
}

__global__ void k_initcoord(const float* __restrict__ x, float* __restrict__ coord)
{
  int i = blockIdx.x * blockDim.x + threadIdx.x;
  if (i >= NN * 2) return;
  coord[i] = x[(size_t)(i >> 1)*7 + (i & 1)];
}

__global__ void k_concat_inp(const float* __restrict__ coord,
                             const float* __restrict__ hidden,
                             float* __restrict__ inp)
{
  int i = blockIdx.x * blockDim.x + threadIdx.x;
  if (i >= NN * GIND) return;
  int n = i / GIND, c = i - GIND*n;
  inp[i] = (c < 2) ? coord[(size_t)n*2 + c] : hidden[(size_t)n*HIDD + c - 2];
}

// ---------------------------------------------------------------------------
// CSR build (by dst). dst for e>=NEDGE is the self-loop e-NEDGE.
// ---------------------------------------------------------------------------
__global__ void k_count(const int* __restrict__ dst, int* __restrict__ cnt)
{
  int e = blockIdx.x * blockDim.x + threadIdx.x;
  if (e >= ELOOP) return;
  int d = (e < NEDGE) ? dst[e] : e - NEDGE;
  atomicAdd(&cnt[d], 1);
}

__global__ __launch_bounds__(1024) void k_scan(const int* __restrict__ cnt,
                                               int* __restrict__ ptr)
{
  __shared__ int part[1024];
  int tid = threadIdx.x;
  const int per = 8;                       // 8*1024 >= NN
  int loc[per]; int s = 0;
  int base = tid * per;
  #pragma unroll
  for (int i = 0; i < per; ++i){
    int v = (base + i < NN) ? cnt[base + i] : 0;
    loc[i] = s; s += v;
  }
  part[tid] = s;
  __syncthreads();
  for (int off = 1; off < 1024; off <<= 1){
    int v = 0;
    if (tid >= off) v = part[tid - off];
    __syncthreads();
    if (tid >= off) part[tid] += v;
    __syncthreads();
  }
  int pre = tid ? part[tid - 1] : 0;
  #pragma unroll
  for (int i = 0; i < per; ++i)
    if (base + i < NN) ptr[base + i] = pre + loc[i];
  if (tid == 1023) ptr[NN] = part[1023];
}

__global__ void k_fill(const int* __restrict__ dst, const int* __restrict__ ptr,
                       int* __restrict__ fil, int* __restrict__ eid)
{
  int e = blockIdx.x * blockDim.x + threadIdx.x;
  if (e >= ELOOP) return;
  int d = (e < NEDGE) ? dst[e] : e - NEDGE;
  int pos = ptr[d] + atomicAdd(&fil[d], 1);
  eid[pos] = e;
}

// ---------------------------------------------------------------------------
// logits[e,h] = sum_c lrelu(xl[src,h,c]+xr[dst,h,c]) * att[h,c]
// one wave per (e,h)
// ---------------------------------------------------------------------------
__global__ __launch_bounds__(256) void k_logits(const float* __restrict__ xl,
    const float* __restrict__ xr, const int* __restrict__ src_a,
    const int* __restrict__ dst_a, const float* __restrict__ att,
    float* __restrict__ logits)
{
  int wid = blockIdx.x * 4 + (threadIdx.x >> 6);
  if (wid >= ELOOP * NHEADS) return;
  int e = wid / NHEADS, h = wid - NHEADS * (wid / NHEADS);
  int lane = threadIdx.x & 63;
  int s = (e < NEDGE) ? src_a[e] : e - NEDGE;
  int d = (e < NEDGE) ? dst_a[e] : e - NEDGE;
  const float* pl = xl + (size_t)s * GOUT + h * HCD;
  const float* pr = xr + (size_t)d * GOUT + h * HCD;
  const float* pa = att + h * HCD;
  float acc = 0.f;
  #pragma unroll
  for (int j = 0; j < 8; ++j){
    int c = j * 64 + lane;
    float v = pl[c] + pr[c];
    v = v > 0.f ? v : 0.2f * v;
    acc = fmaf(v, pa[c], acc);
  }
  #pragma unroll
  for (int o = 32; o; o >>= 1) acc += __shfl_xor(acc, o);
  if (lane == 0) logits[wid] = acc;
}

// mx / inv(sum) per (node, head)
__global__ void k_stats(const float* __restrict__ logits, const int* __restrict__ ptr,
                        const int* __restrict__ eid, float* __restrict__ mx,
                        float* __restrict__ inv)
{
  int i = blockIdx.x * blockDim.x + threadIdx.x;
  if (i >= NN * NHEADS) return;
  int n = i / NHEADS, h = i - NHEADS * n;
  int s0 = ptr[n], s1 = ptr[n + 1];
  float m = -1e30f;
  for (int t = s0; t < s1; ++t) m = fmaxf(m, logits[eid[t]*NHEADS + h]);
  float s = 0.f;
  for (int t = s0; t < s1; ++t) s += __expf(logits[eid[t]*NHEADS + h] - m);
  mx[i] = m; inv[i] = 1.f / s;
}

// ---------------------------------------------------------------------------
// hidden[n,c] = selu(mean_h sum_{e in(n)} a[e,h]*xl[src,h,c] + gbias[c])
// block per node, 256 threads, 12 accumulator slots per thread
// ---------------------------------------------------------------------------
__global__ __launch_bounds__(256) void k_agg(const float* __restrict__ xl,
    const float* __restrict__ logits, const float* __restrict__ mx,
    const float* __restrict__ inv, const int* __restrict__ ptr,
    const int* __restrict__ eid, const int* __restrict__ src_a,
    const float* __restrict__ gbias, float* __restrict__ hidden)
{
  const int n = blockIdx.x;
  const int tid = threadIdx.x;
  __shared__ float a_sh[64 * NHEADS];
  __shared__ int src_sh[64];
  const int s0 = ptr[n];
  const int deg = ptr[n + 1] - s0;
  float acc[12] = {};
  for (int base = 0; base < deg; base += 64){
    int cnt = min(64, deg - base);
    __syncthreads();
    for (int t = tid; t < cnt * NHEADS; t += 256){
      int ei = t / NHEADS, h = t - NHEADS * ei;
      int e = eid[s0 + base + ei];
      a_sh[t] = __expf(logits[e*NHEADS + h] - mx[n*NHEADS + h]) * inv[n*NHEADS + h];
      if (h == 0) src_sh[ei] = (e < NEDGE) ? src_a[e] : e - NEDGE;
    }
    __syncthreads();
    for (int i2 = 0; i2 < cnt; ++i2){
      const float* row = xl + (size_t)src_sh[i2] * GOUT;
      #pragma unroll
      for (int k = 0; k < 12; ++k){
        int slot = tid + (k << 8);
        acc[k] = fmaf(row[slot], a_sh[i2*NHEADS + (slot >> 9)], acc[k]);
      }
    }
  }
  float m1 = (acc[0]+acc[2]+acc[4]+acc[6]+acc[8]+acc[10]) * (1.f/6.f);
  float m2 = (acc[1]+acc[3]+acc[5]+acc[7]+acc[9]+acc[11]) * (1.f/6.f);
  hidden[(size_t)n*HIDD + tid]       = selu_f(m1 + gbias[tid]);
  hidden[(size_t)n*HIDD + 256 + tid] = selu_f(m2 + gbias[256 + tid]);
}

// ---------------------------------------------------------------------------
extern "C" void kernel_launch(void* const* d_in, const int* in_sizes, int n_in,
                              void* d_out, int out_size, void* d_ws, size_t ws_size,
                              hipStream_t stream)
{
  const float* mesh     = (const float*)d_in[1];
  const float* xin      = (const float*)d_in[2];
  const int*   ei       = (const int*)d_in[3];
  const float* embed_w  = (const float*)d_in[4];
  const float* embed_b  = (const float*)d_in[5];
  const float* in_proj_w= (const float*)d_in[6];
  const float* in_proj_b= (const float*)d_in[7];
  const float* out_proj_w=(const float*)d_in[8];
  const float* out_proj_b=(const float*)d_in[9];
  const float* ln1_g    = (const float*)d_in[10];
  const float* ln1_b    = (const float*)d_in[11];
  const float* ln2_g    = (const float*)d_in[12];
  const float* ln2_b    = (const float*)d_in[13];
  const float* ff1_w    = (const float*)d_in[14];
  const float* ff1_b    = (const float*)d_in[15];
  const float* ff2_w    = (const float*)d_in[16];
  const float* ff2_b    = (const float*)d_in[17];
  const float* tout_w   = (const float*)d_in[18];
  const float* tout_b   = (const float*)d_in[19];
  const float* lin_w    = (const float*)d_in[20];
  const float* lin_b    = (const float*)d_in[21];
  const float* gat_wl   = (const float*)d_in[22];
  const float* gat_bl   = (const float*)d_in[23];
  const float* gat_wr   = (const float*)d_in[24];
  const float* gat_br   = (const float*)d_in[25];
  const float* gat_att  = (const float*)d_in[26];
  const float* gat_bias = (const float*)d_in[27];
  const float* coord1_w = (const float*)d_in[28];
  const float* coord1_b = (const float*)d_in[29];
  const float* coord2_w = (const float*)d_in[30];
  const float* coord2_b = (const float*)d_in[31];

  const int* esrc = ei;
  const int* edst = ei + NEDGE;

  char* ws = (char*)d_ws;
  size_t off = 0;
  auto alloc = [&](size_t nbytes){
    size_t o = off; off += (nbytes + 255) & ~(size_t)255; return o;
  };
  float* hidden = (float*)(ws + alloc((size_t)NN * HIDD * 4));
  float* coord  = (float*)(ws + alloc((size_t)NN * 2 * 4));
  float* xl     = (float*)(ws + alloc((size_t)NN * GOUT * 4));
  float* xr     = (float*)(ws + alloc((size_t)NN * GOUT * 4));
  float* inp    = (float*)(ws + alloc((size_t)NN * GIND * 4));
  float* logits = (float*)(ws + alloc((size_t)ELOOP * NHEADS * 4));
  float* mxb    = (float*)(ws + alloc((size_t)NN * NHEADS * 4));
  float* invb   = (float*)(ws + alloc((size_t)NN * NHEADS * 4));
  float* c1     = (float*)(ws + alloc((size_t)NN * 256 * 4));
  int*   ptr    = (int*)(ws + alloc((size_t)(NN + 1) * 4));
  int*   eid    = (int*)(ws + alloc((size_t)ELOOP * 4));
  int*   cnt    = (int*)(ws + alloc((size_t)NN * 4));
  int*   fil    = (int*)(ws + alloc((size_t)NN * 4));

  // phase-A temporaries aliased inside xl / xr (free before GAT loop)
  float* h     = (float*)((char*)xl + 0);
  float* qkv   = (float*)((char*)xl + (4u << 20));
  float* o     = (float*)((char*)xl + (12u << 20));
  float* tmp   = (float*)((char*)xl + (16u << 20));
  float* feats = (float*)((char*)xl + (20u << 20));
  float* toutb = (float*)((char*)xl + (24u << 20));
  float* ffmid = xr;

  // ---- transformer ----
  k_embed<<<CDIV(NN*DTR, 256), 256, 0, stream>>>(mesh, embed_w, embed_b, h);
  k_gemm<0><<<dim3(CDIV(192,64), CDIV(NN,64)), 256, 0, stream>>>(h, in_proj_w, in_proj_b, qkv, NN, 192, DTR);
  k_attn<<<dim3(CDIV(SEQ,128), BATCH, NHTR), 128, 0, stream>>>(qkv, o);
  k_gemm<0><<<dim3(1, CDIV(NN,64)), 256, 0, stream>>>(o, out_proj_w, out_proj_b, tmp, NN, DTR, DTR);
  k_addln<<<CDIV(NN,4), 256, 0, stream>>>(h, tmp, ln1_g, ln1_b, h);
  k_gemm<1><<<dim3(CDIV(FFD,64), CDIV(NN,64)), 256, 0, stream>>>(h, ff1_w, ff1_b, ffmid, NN, FFD, DTR);
  k_gemm<0><<<dim3(1, CDIV(NN,64)), 256, 0, stream>>>(ffmid, ff2_w, ff2_b, tmp, NN, DTR, FFD);
  k_addln<<<CDIV(NN,4), 256, 0, stream>>>(h, tmp, ln2_g, ln2_b, h);
  k_gemm<0><<<dim3(1, CDIV(NN,64)), 256, 0, stream>>>(h, tout_w, tout_b, toutb, NN, TOUTD, DTR);
  k_concat_feats<<<CDIV(NN*21, 256), 256, 0, stream>>>(xin, toutb, feats);
  k_gemm<2><<<dim3(CDIV(HIDD,64), CDIV(NN,64)), 256, 0, stream>>>(feats, lin_w, lin_b, hidden, NN, HIDD, 21);
  k_initcoord<<<CDIV(NN*2, 256), 256, 0, stream>>>(xin, coord);

  // ---- CSR by dst (fixed across loops) ----
  hipMemsetAsync(cnt, 0, (size_t)NN * 4, stream);
  hipMemsetAsync(fil, 0, (size_t)NN * 4, stream);
  k_count<<<CDIV(ELOOP, 256), 256, 0, stream>>>(edst, cnt);
  k_scan<<<1, 1024, 0, stream>>>(cnt, ptr);
  k_fill<<<CDIV(ELOOP, 256), 256, 0, stream>>>(edst, ptr, fil, eid);

  // ---- GAT loops ----
  for (int it = 0; it < 3; ++it){
    k_concat_inp<<<CDIV(NN*GIND, 256), 256, 0, stream>>>(coord, hidden, inp);
    k_gemm<0><<<dim3(CDIV(GOUT,64), CDIV(NN,64)), 256, 0, stream>>>(inp, gat_wl, gat_bl, xl, NN, GOUT, GIND);
    k_gemm<0><<<dim3(CDIV(GOUT,64), CDIV(NN,64)), 256, 0, stream>>>(inp, gat_wr, gat_br, xr, NN, GOUT, GIND);
    k_logits<<<CDIV(ELOOP*NHEADS, 4), 256, 0, stream>>>(xl, xr, esrc, edst, gat_att, logits);
    k_stats<<<CDIV(NN*NHEADS, 256), 256, 0, stream>>>(logits, ptr, eid, mxb, invb);
    k_agg<<<NN, 256, 0, stream>>>(xl, logits, mxb, invb, ptr, eid, esrc, gat_bias, hidden);
    k_gemm<2><<<dim3(CDIV(256,64), CDIV(NN,64)), 256, 0, stream>>>(hidden, coord1_w, coord1_b, c1, NN, 256, HIDD);
    float* cdst = (it == 2) ? (float*)d_out : coord;
    k_gemm<0><<<dim3(1, CDIV(NN,64)), 256, 0, stream>>>(c1, coord2_w, coord2_b, cdst, NN, 2, 256);
  }
}

// Round 2
// 2376.660 us; speedup vs baseline: 1.7674x; 1.7674x over previous
//
#include <hip/hip_runtime.h>
#include <hip/hip_bf16.h>
#include <math.h>

#define NN     8000
#define MPAD   8064    /* NN padded to 128 */
#define BATCH  4
#define SEQ    2000
#define DTR    64
#define NHTR   4
#define DHD    16
#define FFD    2048
#define TOUTD  16
#define HIDD   512
#define NHEADS 6
#define HCD    512
#define GIND   514
#define GOUT   3072
#define NEDGE  32000
#define ELOOP  40000   /* NEDGE + NN */

#define K1     576     /* GIND padded to 64-multiple */
#define K2     1152    /* hi + lo halves */

#define CDIV(a,b) (((a)+(b)-1)/(b))

using bf16x8 = __attribute__((__ext_vector_type__(8))) __bf16;
using f32x4  = __attribute__((__ext_vector_type__(4))) float;

__device__ __forceinline__ float selu_f(float x){
  const float a = 1.6732632423543772848f;
  const float s = 1.0507009873554805f;
  return x > 0.f ? s * x : s * a * (__expf(x) - 1.f);
}

__device__ __forceinline__ unsigned short f2bf_rn(float x){
  unsigned u = __float_as_uint(x);
  unsigned r = (u + 0x7fffu + ((u >> 16) & 1u)) >> 16;
  return (unsigned short)r;
}
__device__ __forceinline__ float bf2f(unsigned short h){
  return __uint_as_float((unsigned)h << 16);
}

// ---------------------------------------------------------------------------
// Generic C[M,N] = act(A[M,K] @ W[N,K]^T + bias). fp32, 64x64 tile, BK=16.
// (kept for the small transformer / coord GEMMs)
// ---------------------------------------------------------------------------
template<int ACT>  // 0=none 1=relu 2=selu
__global__ __launch_bounds__(256) void k_gemm(const float* __restrict__ A,
    const float* __restrict__ W, const float* __restrict__ bias,
    float* __restrict__ C, int M, int N, int K)
{
  __shared__ float As[16][68];
  __shared__ float Ws[16][68];
  const int tid = threadIdx.x;
  const int bm = blockIdx.y * 64, bn = blockIdx.x * 64;
  const int tx = tid & 15, ty = tid >> 4;
  float acc[4][4] = {};
  for (int k0 = 0; k0 < K; k0 += 16){
    #pragma unroll
    for (int i = 0; i < 4; ++i){
      int el = tid + (i << 8);
      int kk = el & 15, r = el >> 4;
      int gk = k0 + kk;
      int gm = bm + r;
      As[kk][r] = (gm < M && gk < K) ? A[(size_t)gm * K + gk] : 0.f;
      int gn = bn + r;
      Ws[kk][r] = (gn < N && gk < K) ? W[(size_t)gn * K + gk] : 0.f;
    }
    __syncthreads();
    #pragma unroll
    for (int kk = 0; kk < 16; ++kk){
      float av[4], wv[4];
      #pragma unroll
      for (int i = 0; i < 4; ++i) av[i] = As[kk][ty*4+i];
      #pragma unroll
      for (int j = 0; j < 4; ++j) wv[j] = Ws[kk][tx*4+j];
      #pragma unroll
      for (int i = 0; i < 4; ++i)
        #pragma unroll
        for (int j = 0; j < 4; ++j) acc[i][j] = fmaf(av[i], wv[j], acc[i][j]);
    }
    __syncthreads();
  }
  #pragma unroll
  for (int i = 0; i < 4; ++i){
    int gm = bm + ty*4 + i;
    if (gm >= M) continue;
    #pragma unroll
    for (int j = 0; j < 4; ++j){
      int gn = bn + tx*4 + j;
      if (gn >= N) continue;
      float v = acc[i][j] + bias[gn];
      if (ACT == 1) v = fmaxf(v, 0.f);
      if (ACT == 2) v = selu_f(v);
      C[(size_t)gm * N + gn] = v;
    }
  }
}

// ---------------------------------------------------------------------------
// weight fp32 [3072][514] -> bf16 split [3072][K2] = [hi(576) | lo(576)]
// ---------------------------------------------------------------------------
__global__ void k_cvt_w(const float* __restrict__ W, short* __restrict__ Wbf)
{
  int i = blockIdx.x * blockDim.x + threadIdx.x;
  if (i >= GOUT * K1) return;
  int n = i / K1, k = i - K1 * n;
  float v = (k < GIND) ? W[(size_t)n * GIND + k] : 0.f;
  unsigned short h = f2bf_rn(v);
  unsigned short l = f2bf_rn(v - bf2f(h));
  Wbf[(size_t)n * K2 + k]      = (short)h;
  Wbf[(size_t)n * K2 + K1 + k] = (short)l;
}

// A = [coord | hidden] fp32 -> bf16 split [MPAD][K2] (pad rows/cols zero)
__global__ void k_cvt_a(const float* __restrict__ coord,
                        const float* __restrict__ hidden,
                        short* __restrict__ Abf)
{
  int i = blockIdx.x * blockDim.x + threadIdx.x;
  if (i >= MPAD * K1) return;
  int n = i / K1, k = i - K1 * n;
  float v = 0.f;
  if (n < NN && k < GIND)
    v = (k < 2) ? coord[(size_t)n*2 + k] : hidden[(size_t)n*HIDD + k - 2];
  unsigned short h = f2bf_rn(v);
  unsigned short l = f2bf_rn(v - bf2f(h));
  Abf[(size_t)n * K2 + k]      = (short)h;
  Abf[(size_t)n * K2 + K1 + k] = (short)l;
}

// ---------------------------------------------------------------------------
// GAT GEMM via MFMA bf16, 3-pass hi/lo split (K-expansion, 27 K-tiles of 64):
//  tiles 0-8:  a_hi * b_hi ; 9-17: a_lo * b_hi ; 18-26: a_hi * b_lo
// 128x128 tile, 4 waves, global_load_lds(16B), 2-barrier loop (m97 structure)
// C[M=8000][3072] = A'' @ W''^T + bias
// ---------------------------------------------------------------------------
__global__ __launch_bounds__(256) void k_gat_mfma(
    const short* __restrict__ Abf, const short* __restrict__ Wbf,
    const float* __restrict__ bias, float* __restrict__ C)
{
  __shared__ short As[128 * 64];
  __shared__ short Bs[128 * 64];
  const int tid  = threadIdx.x;
  const int bm   = blockIdx.y * 128, bn = blockIdx.x * 128;
  const int w    = tid >> 6, lane = tid & 63;
  const int wr   = w >> 1, wc = w & 1;
  const int lrow = lane & 15, lk = (lane >> 4) * 8;

  f32x4 acc[4][4];
  #pragma unroll
  for (int i = 0; i < 4; ++i)
    #pragma unroll
    for (int j = 0; j < 4; ++j) acc[i][j] = (f32x4){0.f, 0.f, 0.f, 0.f};

  for (int kt = 0; kt < 27; ++kt){
    int aoff, boff;
    if (kt < 9)       { aoff = kt * 64;             boff = kt * 64; }
    else if (kt < 18) { aoff = K1 + (kt - 9) * 64;  boff = (kt - 9) * 64; }
    else              { aoff = (kt - 18) * 64;      boff = K1 + (kt - 18) * 64; }
    __syncthreads();                 // previous tile fully consumed
    #pragma unroll
    for (int i = 0; i < 4; ++i){
      int l  = i * 256 + tid;        // 16B-chunk index 0..1023
      int r  = l >> 3, c = (l & 7) * 8;
      const short* ga = Abf + (size_t)(bm + r) * K2 + aoff + c;
      const short* gb = Wbf + (size_t)(bn + r) * K2 + boff + c;
      short* la = As + ((i * 256 + w * 64) << 3);   // wave-uniform base
      short* lb = Bs + ((i * 256 + w * 64) << 3);
      __builtin_amdgcn_global_load_lds(
          (const __attribute__((address_space(1))) unsigned*)ga,
          (__attribute__((address_space(3))) unsigned*)la, 16, 0, 0);
      __builtin_amdgcn_global_load_lds(
          (const __attribute__((address_space(1))) unsigned*)gb,
          (__attribute__((address_space(3))) unsigned*)lb, 16, 0, 0);
    }
    __syncthreads();                 // drains vmcnt, tile ready
    #pragma unroll
    for (int ks = 0; ks < 2; ++ks){
      bf16x8 fa[4], fb[4];
      #pragma unroll
      for (int mi = 0; mi < 4; ++mi)
        fa[mi] = *(const bf16x8*)&As[(wr*64 + mi*16 + lrow) * 64 + ks*32 + lk];
      #pragma unroll
      for (int ni = 0; ni < 4; ++ni)
        fb[ni] = *(const bf16x8*)&Bs[(wc*64 + ni*16 + lrow) * 64 + ks*32 + lk];
      #pragma unroll
      for (int mi = 0; mi < 4; ++mi)
        #pragma unroll
        for (int ni = 0; ni < 4; ++ni)
          acc[mi][ni] = __builtin_amdgcn_mfma_f32_16x16x32_bf16(
              fa[mi], fb[ni], acc[mi][ni], 0, 0, 0);
    }
  }
  // epilogue: C[row][col], col = lane&15 (+n), row = (lane>>4)*4 + j (+m)
  #pragma unroll
  for (int mi = 0; mi < 4; ++mi){
    #pragma unroll
    for (int ni = 0; ni < 4; ++ni){
      int gn = bn + wc*64 + ni*16 + lrow;
      float bv = bias[gn];
      #pragma unroll
      for (int j = 0; j < 4; ++j){
        int gm = bm + wr*64 + mi*16 + (lane >> 4) * 4 + j;
        if (gm < NN)
          C[(size_t)gm * GOUT + gn] = acc[mi][ni][j] + bv;
      }
    }
  }
}

// ---------------------------------------------------------------------------
// h[n,d] = mesh[n,0:4] . embed_w[d,0:4] + embed_b[d]
// ---------------------------------------------------------------------------
__global__ void k_embed(const float* __restrict__ mesh,
                        const float* __restrict__ w, const float* __restrict__ b,
                        float* __restrict__ h)
{
  int i = blockIdx.x * blockDim.x + threadIdx.x;
  if (i >= NN * DTR) return;
  int n = i >> 6, d = i & 63;
  const float* mr = mesh + n * 4;
  const float* wr = w + d * 4;
  h[i] = fmaf(mr[0], wr[0], fmaf(mr[1], wr[1], fmaf(mr[2], wr[2], mr[3]*wr[3]))) + b[d];
}

// ---------------------------------------------------------------------------
// attention: thread per query, flash-style over LDS K/V tiles of 128 keys
// ---------------------------------------------------------------------------
__global__ __launch_bounds__(128) void k_attn(const float* __restrict__ qkv,
                                              float* __restrict__ o)
{
  __shared__ float Ks[128][DHD];
  __shared__ float Vs[128][DHD];
  const int q = blockIdx.x * 128 + threadIdx.x;
  const int b = blockIdx.y, h = blockIdx.z;
  const bool valid = q < SEQ;
  float qv[DHD];
  if (valid){
    #pragma unroll
    for (int d = 0; d < DHD; ++d)
      qv[d] = qkv[((size_t)(b*SEQ + q))*192 + h*DHD + d];
  }
  float m = -1e30f, l = 0.f, acc[DHD] = {};
  for (int kt = 0; kt < SEQ; kt += 128){
    int cnt = min(128, SEQ - kt);
    __syncthreads();
    for (int el = threadIdx.x; el < cnt * DHD; el += 128){
      int r = el >> 4, d = el & 15;
      size_t base = ((size_t)(b*SEQ + kt + r))*192 + h*DHD + d;
      Ks[r][d] = qkv[base + 64];
      Vs[r][d] = qkv[base + 128];
    }
    __syncthreads();
    if (valid){
      for (int r = 0; r < cnt; ++r){
        float s = 0.f;
        #pragma unroll
        for (int d = 0; d < DHD; ++d) s = fmaf(qv[d], Ks[r][d], s);
        s *= 0.25f;
        float mn = fmaxf(m, s);
        float cc = __expf(m - mn), p = __expf(s - mn);
        l = l * cc + p;
        #pragma unroll
        for (int d = 0; d < DHD; ++d) acc[d] = fmaf(acc[d], cc, p * Vs[r][d]);
        m = mn;
      }
    }
  }
  if (valid){
    float inv = 1.f / l;
    #pragma unroll
    for (int d = 0; d < DHD; ++d)
      o[((size_t)(b*SEQ + q))*64 + h*DHD + d] = acc[d] * inv;
  }
}

// ---------------------------------------------------------------------------
__global__ __launch_bounds__(256) void k_addln(const float* __restrict__ x,
    const float* __restrict__ y, const float* __restrict__ g,
    const float* __restrict__ b, float* __restrict__ out)
{
  int row = blockIdx.x * 4 + (threadIdx.x >> 6);
  int lane = threadIdx.x & 63;
  if (row >= NN) return;
  float v = x[(size_t)row*64 + lane] + y[(size_t)row*64 + lane];
  float s1 = v, s2 = v * v;
  #pragma unroll
  for (int o = 32; o; o >>= 1){ s1 += __shfl_xor(s1, o); s2 += __shfl_xor(s2, o); }
  float mean = s1 * (1.f/64.f);
  float var  = s2 * (1.f/64.f) - mean * mean;
  float r = rsqrtf(var + 1e-5f);
  out[(size_t)row*64 + lane] = (v - mean) * r * g[lane] + b[lane];
}

__global__ void k_concat_feats(const float* __restrict__ x,
                               const float* __restrict__ tout,
                               float* __restrict__ feats)
{
  int i = blockIdx.x * blockDim.x + threadIdx.x;
  if (i >= NN * 21) return;
  int n = i / 21, c = i - 21*n;
  feats[i] = (c < 5) ? x[(size_t)n*7 + 2 + c] : tout[(size_t)n*16 + c - 5];
}

__global__ void k_initcoord(const float* __restrict__ x, float* __restrict__ coord)
{
  int i = blockIdx.x * blockDim.x + threadIdx.x;
  if (i >= NN * 2) return;
  coord[i] = x[(size_t)(i >> 1)*7 + (i & 1)];
}

// ---------------------------------------------------------------------------
// CSR build (by dst). dst for e>=NEDGE is the self-loop e-NEDGE.
// ---------------------------------------------------------------------------
__global__ void k_count(const int* __restrict__ dst, int* __restrict__ cnt)
{
  int e = blockIdx.x * blockDim.x + threadIdx.x;
  if (e >= ELOOP) return;
  int d = (e < NEDGE) ? dst[e] : e - NEDGE;
  atomicAdd(&cnt[d], 1);
}

__global__ __launch_bounds__(1024) void k_scan(const int* __restrict__ cnt,
                                               int* __restrict__ ptr)
{
  __shared__ int part[1024];
  int tid = threadIdx.x;
  const int per = 8;
  int loc[per]; int s = 0;
  int base = tid * per;
  #pragma unroll
  for (int i = 0; i < per; ++i){
    int v = (base + i < NN) ? cnt[base + i] : 0;
    loc[i] = s; s += v;
  }
  part[tid] = s;
  __syncthreads();
  for (int off = 1; off < 1024; off <<= 1){
    int v = 0;
    if (tid >= off) v = part[tid - off];
    __syncthreads();
    if (tid >= off) part[tid] += v;
    __syncthreads();
  }
  int pre = tid ? part[tid - 1] : 0;
  #pragma unroll
  for (int i = 0; i < per; ++i)
    if (base + i < NN) ptr[base + i] = pre + loc[i];
  if (tid == 1023) ptr[NN] = part[1023];
}

__global__ void k_fill(const int* __restrict__ dst, const int* __restrict__ ptr,
                       int* __restrict__ fil, int* __restrict__ eid)
{
  int e = blockIdx.x * blockDim.x + threadIdx.x;
  if (e >= ELOOP) return;
  int d = (e < NEDGE) ? dst[e] : e - NEDGE;
  int pos = ptr[d] + atomicAdd(&fil[d], 1);
  eid[pos] = e;
}

// ---------------------------------------------------------------------------
// logits[e,h] = sum_c lrelu(xl[src,h,c]+xr[dst,h,c]) * att[h,c]; wave/(e,h)
// ---------------------------------------------------------------------------
__global__ __launch_bounds__(256) void k_logits(const float* __restrict__ xl,
    const float* __restrict__ xr, const int* __restrict__ src_a,
    const int* __restrict__ dst_a, const float* __restrict__ att,
    float* __restrict__ logits)
{
  int wid = blockIdx.x * 4 + (threadIdx.x >> 6);
  if (wid >= ELOOP * NHEADS) return;
  int e = wid / NHEADS, h = wid - NHEADS * (wid / NHEADS);
  int lane = threadIdx.x & 63;
  int s = (e < NEDGE) ? src_a[e] : e - NEDGE;
  int d = (e < NEDGE) ? dst_a[e] : e - NEDGE;
  const float* pl = xl + (size_t)s * GOUT + h * HCD;
  const float* pr = xr + (size_t)d * GOUT + h * HCD;
  const float* pa = att + h * HCD;
  float acc = 0.f;
  #pragma unroll
  for (int j = 0; j < 8; ++j){
    int c = j * 64 + lane;
    float v = pl[c] + pr[c];
    v = v > 0.f ? v : 0.2f * v;
    acc = fmaf(v, pa[c], acc);
  }
  #pragma unroll
  for (int o = 32; o; o >>= 1) acc += __shfl_xor(acc, o);
  if (lane == 0) logits[wid] = acc;
}

__global__ void k_stats(const float* __restrict__ logits, const int* __restrict__ ptr,
                        const int* __restrict__ eid, float* __restrict__ mx,
                        float* __restrict__ inv)
{
  int i = blockIdx.x * blockDim.x + threadIdx.x;
  if (i >= NN * NHEADS) return;
  int n = i / NHEADS, h = i - NHEADS * n;
  int s0 = ptr[n], s1 = ptr[n + 1];
  float m = -1e30f;
  for (int t = s0; t < s1; ++t) m = fmaxf(m, logits[eid[t]*NHEADS + h]);
  float s = 0.f;
  for (int t = s0; t < s1; ++t) s += __expf(logits[eid[t]*NHEADS + h] - m);
  mx[i] = m; inv[i] = 1.f / s;
}

// ---------------------------------------------------------------------------
// hidden[n,c] = selu(mean_h sum_{e in(n)} a[e,h]*xl[src,h,c] + gbias[c])
// ---------------------------------------------------------------------------
__global__ __launch_bounds__(256) void k_agg(const float* __restrict__ xl,
    const float* __restrict__ logits, const float* __restrict__ mx,
    const float* __restrict__ inv, const int* __restrict__ ptr,
    const int* __restrict__ eid, const int* __restrict__ src_a,
    const float* __restrict__ gbias, float* __restrict__ hidden)
{
  const int n = blockIdx.x;
  const int tid = threadIdx.x;
  __shared__ float a_sh[64 * NHEADS];
  __shared__ int src_sh[64];
  const int s0 = ptr[n];
  const int deg = ptr[n + 1] - s0;
  float acc[12] = {};
  for (int base = 0; base < deg; base += 64){
    int cnt = min(64, deg - base);
    __syncthreads();
    for (int t = tid; t < cnt * NHEADS; t += 256){
      int ei = t / NHEADS, h = t - NHEADS * ei;
      int e = eid[s0 + base + ei];
      a_sh[t] = __expf(logits[e*NHEADS + h] - mx[n*NHEADS + h]) * inv[n*NHEADS + h];
      if (h == 0) src_sh[ei] = (e < NEDGE) ? src_a[e] : e - NEDGE;
    }
    __syncthreads();
    for (int i2 = 0; i2 < cnt; ++i2){
      const float* row = xl + (size_t)src_sh[i2] * GOUT;
      #pragma unroll
      for (int k = 0; k < 12; ++k){
        int slot = tid + (k << 8);
        acc[k] = fmaf(row[slot], a_sh[i2*NHEADS + (slot >> 9)], acc[k]);
      }
    }
  }
  float m1 = (acc[0]+acc[2]+acc[4]+acc[6]+acc[8]+acc[10]) * (1.f/6.f);
  float m2 = (acc[1]+acc[3]+acc[5]+acc[7]+acc[9]+acc[11]) * (1.f/6.f);
  hidden[(size_t)n*HIDD + tid]       = selu_f(m1 + gbias[tid]);
  hidden[(size_t)n*HIDD + 256 + tid] = selu_f(m2 + gbias[256 + tid]);
}

// ---------------------------------------------------------------------------
extern "C" void kernel_launch(void* const* d_in, const int* in_sizes, int n_in,
                              void* d_out, int out_size, void* d_ws, size_t ws_size,
                              hipStream_t stream)
{
  const float* mesh     = (const float*)d_in[1];
  const float* xin      = (const float*)d_in[2];
  const int*   ei       = (const int*)d_in[3];
  const float* embed_w  = (const float*)d_in[4];
  const float* embed_b  = (const float*)d_in[5];
  const float* in_proj_w= (const float*)d_in[6];
  const float* in_proj_b= (const float*)d_in[7];
  const float* out_proj_w=(const float*)d_in[8];
  const float* out_proj_b=(const float*)d_in[9];
  const float* ln1_g    = (const float*)d_in[10];
  const float* ln1_b    = (const float*)d_in[11];
  const float* ln2_g    = (const float*)d_in[12];
  const float* ln2_b    = (const float*)d_in[13];
  const float* ff1_w    = (const float*)d_in[14];
  const float* ff1_b    = (const float*)d_in[15];
  const float* ff2_w    = (const float*)d_in[16];
  const float* ff2_b    = (const float*)d_in[17];
  const float* tout_w   = (const float*)d_in[18];
  const float* tout_b   = (const float*)d_in[19];
  const float* lin_w    = (const float*)d_in[20];
  const float* lin_b    = (const float*)d_in[21];
  const float* gat_wl   = (const float*)d_in[22];
  const float* gat_bl   = (const float*)d_in[23];
  const float* gat_wr   = (const float*)d_in[24];
  const float* gat_br   = (const float*)d_in[25];
  const float* gat_att  = (const float*)d_in[26];
  const float* gat_bias = (const float*)d_in[27];
  const float* coord1_w = (const float*)d_in[28];
  const float* coord1_b = (const float*)d_in[29];
  const float* coord2_w = (const float*)d_in[30];
  const float* coord2_b = (const float*)d_in[31];

  const int* esrc = ei;
  const int* edst = ei + NEDGE;

  char* ws = (char*)d_ws;
  size_t off = 0;
  auto alloc = [&](size_t nbytes){
    size_t o = off; off += (nbytes + 255) & ~(size_t)255; return o;
  };
  float* hidden = (float*)(ws + alloc((size_t)NN * HIDD * 4));
  float* coord  = (float*)(ws + alloc((size_t)NN * 2 * 4));
  float* xl     = (float*)(ws + alloc((size_t)NN * GOUT * 4));
  float* xr     = (float*)(ws + alloc((size_t)NN * GOUT * 4));
  float* logits = (float*)(ws + alloc((size_t)ELOOP * NHEADS * 4));
  float* mxb    = (float*)(ws + alloc((size_t)NN * NHEADS * 4));
  float* invb   = (float*)(ws + alloc((size_t)NN * NHEADS * 4));
  float* c1     = (float*)(ws + alloc((size_t)NN * 256 * 4));
  int*   ptr    = (int*)(ws + alloc((size_t)(NN + 1) * 4));
  int*   eid    = (int*)(ws + alloc((size_t)ELOOP * 4));
  int*   cnt    = (int*)(ws + alloc((size_t)NN * 4));
  int*   fil    = (int*)(ws + alloc((size_t)NN * 4));
  short* abf    = (short*)(ws + alloc((size_t)MPAD * K2 * 2));
  short* wlbf   = (short*)(ws + alloc((size_t)GOUT * K2 * 2));
  short* wrbf   = (short*)(ws + alloc((size_t)GOUT * K2 * 2));

  // phase-A temporaries aliased inside xl (free before GAT loop)
  float* h     = (float*)((char*)xl + 0);
  float* qkv   = (float*)((char*)xl + (4u << 20));
  float* o     = (float*)((char*)xl + (12u << 20));
  float* tmp   = (float*)((char*)xl + (16u << 20));
  float* feats = (float*)((char*)xl + (20u << 20));
  float* toutb = (float*)((char*)xl + (24u << 20));
  float* ffmid = xr;

  // ---- transformer ----
  k_embed<<<CDIV(NN*DTR, 256), 256, 0, stream>>>(mesh, embed_w, embed_b, h);
  k_gemm<0><<<dim3(CDIV(192,64), CDIV(NN,64)), 256, 0, stream>>>(h, in_proj_w, in_proj_b, qkv, NN, 192, DTR);
  k_attn<<<dim3(CDIV(SEQ,128), BATCH, NHTR), 128, 0, stream>>>(qkv, o);
  k_gemm<0><<<dim3(1, CDIV(NN,64)), 256, 0, stream>>>(o, out_proj_w, out_proj_b, tmp, NN, DTR, DTR);
  k_addln<<<CDIV(NN,4), 256, 0, stream>>>(h, tmp, ln1_g, ln1_b, h);
  k_gemm<1><<<dim3(CDIV(FFD,64), CDIV(NN,64)), 256, 0, stream>>>(h, ff1_w, ff1_b, ffmid, NN, FFD, DTR);
  k_gemm<0><<<dim3(1, CDIV(NN,64)), 256, 0, stream>>>(ffmid, ff2_w, ff2_b, tmp, NN, DTR, FFD);
  k_addln<<<CDIV(NN,4), 256, 0, stream>>>(h, tmp, ln2_g, ln2_b, h);
  k_gemm<0><<<dim3(1, CDIV(NN,64)), 256, 0, stream>>>(h, tout_w, tout_b, toutb, NN, TOUTD, DTR);
  k_concat_feats<<<CDIV(NN*21, 256), 256, 0, stream>>>(xin, toutb, feats);
  k_gemm<2><<<dim3(CDIV(HIDD,64), CDIV(NN,64)), 256, 0, stream>>>(feats, lin_w, lin_b, hidden, NN, HIDD, 21);
  k_initcoord<<<CDIV(NN*2, 256), 256, 0, stream>>>(xin, coord);

  // ---- CSR by dst + weight conversion (once) ----
  hipMemsetAsync(cnt, 0, (size_t)NN * 4, stream);
  hipMemsetAsync(fil, 0, (size_t)NN * 4, stream);
  k_count<<<CDIV(ELOOP, 256), 256, 0, stream>>>(edst, cnt);
  k_scan<<<1, 1024, 0, stream>>>(cnt, ptr);
  k_fill<<<CDIV(ELOOP, 256), 256, 0, stream>>>(edst, ptr, fil, eid);
  k_cvt_w<<<CDIV(GOUT*K1, 256), 256, 0, stream>>>(gat_wl, wlbf);
  k_cvt_w<<<CDIV(GOUT*K1, 256), 256, 0, stream>>>(gat_wr, wrbf);

  // ---- GAT loops ----
  for (int it = 0; it < 3; ++it){
    k_cvt_a<<<CDIV(MPAD*K1, 256), 256, 0, stream>>>(coord, hidden, abf);
    k_gat_mfma<<<dim3(GOUT/128, MPAD/128), 256, 0, stream>>>(abf, wlbf, gat_bl, xl);
    k_gat_mfma<<<dim3(GOUT/128, MPAD/128), 256, 0, stream>>>(abf, wrbf, gat_br, xr);
    k_logits<<<CDIV(ELOOP*NHEADS, 4), 256, 0, stream>>>(xl, xr, esrc, edst, gat_att, logits);
    k_stats<<<CDIV(NN*NHEADS, 256), 256, 0, stream>>>(logits, ptr, eid, mxb, invb);
    k_agg<<<NN, 256, 0, stream>>>(xl, logits, mxb, invb, ptr, eid, esrc, gat_bias, hidden);
    k_gemm<2><<<dim3(CDIV(256,64), CDIV(NN,64)), 256, 0, stream>>>(hidden, coord1_w, coord1_b, c1, NN, 256, HIDD);
    float* cdst = (it == 2) ? (float*)d_out : coord;
    k_gemm<0><<<dim3(1, CDIV(NN,64)), 256, 0, stream>>>(c1, coord2_w, coord2_b, cdst, NN, 2, 256);
  }
}

// Round 5
// 2125.262 us; speedup vs baseline: 1.9765x; 1.1183x over previous
//
#include <hip/hip_runtime.h>
#include <hip/hip_bf16.h>
#include <math.h>

#define NN     8000
#define MPAD   8064    /* NN padded to 128 */
#define BATCH  4
#define SEQ    2000
#define DTR    64
#define NHTR   4
#define DHD    16
#define FFD    2048
#define TOUTD  16
#define HIDD   512
#define NHEADS 6
#define HCD    512
#define GIND   514
#define GOUT   3072
#define NEDGE  32000
#define ELOOP  40000   /* NEDGE + NN */

#define K1     576     /* GIND padded to 64-multiple */
#define K2     1152    /* hi + lo halves */

#define KSPLIT 8
#define KCH    250     /* SEQ / KSPLIT */

#define CDIV(a,b) (((a)+(b)-1)/(b))

using bf16x8 = __attribute__((__ext_vector_type__(8))) __bf16;
using f32x4  = __attribute__((__ext_vector_type__(4))) float;

__device__ __forceinline__ float selu_f(float x){
  const float a = 1.6732632423543772848f;
  const float s = 1.0507009873554805f;
  return x > 0.f ? s * x : s * a * (__expf(x) - 1.f);
}

__device__ __forceinline__ unsigned short f2bf_rn(float x){
  unsigned u = __float_as_uint(x);
  unsigned r = (u + 0x7fffu + ((u >> 16) & 1u)) >> 16;
  return (unsigned short)r;
}
__device__ __forceinline__ float bf2f(unsigned short h){
  return __uint_as_float((unsigned)h << 16);
}

// ---------------------------------------------------------------------------
// Generic C[M,N] = act(A[M,K] @ W[N,K]^T + bias). fp32, 64x64 tile, BK=16.
// (kept for the small transformer / coord GEMMs)
// ---------------------------------------------------------------------------
template<int ACT>  // 0=none 1=relu 2=selu
__global__ __launch_bounds__(256) void k_gemm(const float* __restrict__ A,
    const float* __restrict__ W, const float* __restrict__ bias,
    float* __restrict__ C, int M, int N, int K)
{
  __shared__ float As[16][68];
  __shared__ float Ws[16][68];
  const int tid = threadIdx.x;
  const int bm = blockIdx.y * 64, bn = blockIdx.x * 64;
  const int tx = tid & 15, ty = tid >> 4;
  float acc[4][4] = {};
  for (int k0 = 0; k0 < K; k0 += 16){
    #pragma unroll
    for (int i = 0; i < 4; ++i){
      int el = tid + (i << 8);
      int kk = el & 15, r = el >> 4;
      int gk = k0 + kk;
      int gm = bm + r;
      As[kk][r] = (gm < M && gk < K) ? A[(size_t)gm * K + gk] : 0.f;
      int gn = bn + r;
      Ws[kk][r] = (gn < N && gk < K) ? W[(size_t)gn * K + gk] : 0.f;
    }
    __syncthreads();
    #pragma unroll
    for (int kk = 0; kk < 16; ++kk){
      float av[4], wv[4];
      #pragma unroll
      for (int i = 0; i < 4; ++i) av[i] = As[kk][ty*4+i];
      #pragma unroll
      for (int j = 0; j < 4; ++j) wv[j] = Ws[kk][tx*4+j];
      #pragma unroll
      for (int i = 0; i < 4; ++i)
        #pragma unroll
        for (int j = 0; j < 4; ++j) acc[i][j] = fmaf(av[i], wv[j], acc[i][j]);
    }
    __syncthreads();
  }
  #pragma unroll
  for (int i = 0; i < 4; ++i){
    int gm = bm + ty*4 + i;
    if (gm >= M) continue;
    #pragma unroll
    for (int j = 0; j < 4; ++j){
      int gn = bn + tx*4 + j;
      if (gn >= N) continue;
      float v = acc[i][j] + bias[gn];
      if (ACT == 1) v = fmaxf(v, 0.f);
      if (ACT == 2) v = selu_f(v);
      C[(size_t)gm * N + gn] = v;
    }
  }
}

// ---------------------------------------------------------------------------
// weight fp32 [3072][514] -> bf16 split [3072][K2] = [hi(576) | lo(576)]
// ---------------------------------------------------------------------------
__global__ void k_cvt_w(const float* __restrict__ W, short* __restrict__ Wbf)
{
  int i = blockIdx.x * blockDim.x + threadIdx.x;
  if (i >= GOUT * K1) return;
  int n = i / K1, k = i - K1 * n;
  float v = (k < GIND) ? W[(size_t)n * GIND + k] : 0.f;
  unsigned short h = f2bf_rn(v);
  unsigned short l = f2bf_rn(v - bf2f(h));
  Wbf[(size_t)n * K2 + k]      = (short)h;
  Wbf[(size_t)n * K2 + K1 + k] = (short)l;
}

// A = [coord | hidden] fp32 -> bf16 split [MPAD][K2] = [hi(576) | lo(576)]
__global__ void k_cvt_a(const float* __restrict__ coord,
                        const float* __restrict__ hidden,
                        short* __restrict__ Abf)
{
  int i = blockIdx.x * blockDim.x + threadIdx.x;
  if (i >= MPAD * K1) return;
  int n = i / K1, k = i - K1 * n;
  float v = 0.f;
  if (n < NN && k < GIND)
    v = (k < 2) ? coord[(size_t)n*2 + k] : hidden[(size_t)n*HIDD + k - 2];
  unsigned short h = f2bf_rn(v);
  unsigned short l = f2bf_rn(v - bf2f(h));
  Abf[(size_t)n * K2 + k]      = (short)h;
  Abf[(size_t)n * K2 + K1 + k] = (short)l;
}

// ---------------------------------------------------------------------------
// GAT GEMM via MFMA bf16, 3-pass hi/lo split (K-expansion, 27 K-tiles of 64):
//  tiles 0-8:  a_hi * b_hi ; 9-17: a_lo * b_hi ; 18-26: a_hi * b_lo
// 128x128 tile, 4 waves, global_load_lds(16B), 2-barrier loop (m97 structure)
// ---------------------------------------------------------------------------
__global__ __launch_bounds__(256) void k_gat_mfma(
    const short* __restrict__ Abf, const short* __restrict__ Wbf,
    const float* __restrict__ bias, float* __restrict__ C)
{
  __shared__ short As[128 * 64];
  __shared__ short Bs[128 * 64];
  const int tid  = threadIdx.x;
  const int bm   = blockIdx.y * 128, bn = blockIdx.x * 128;
  const int w    = tid >> 6, lane = tid & 63;
  const int wr   = w >> 1, wc = w & 1;
  const int lrow = lane & 15, lk = (lane >> 4) * 8;

  f32x4 acc[4][4];
  #pragma unroll
  for (int i = 0; i < 4; ++i)
    #pragma unroll
    for (int j = 0; j < 4; ++j) acc[i][j] = (f32x4){0.f, 0.f, 0.f, 0.f};

  for (int kt = 0; kt < 27; ++kt){
    int aoff, boff;
    if (kt < 9)       { aoff = kt * 64;             boff = kt * 64; }
    else if (kt < 18) { aoff = K1 + (kt - 9) * 64;  boff = (kt - 9) * 64; }
    else              { aoff = (kt - 18) * 64;      boff = K1 + (kt - 18) * 64; }
    __syncthreads();                 // previous tile fully consumed
    #pragma unroll
    for (int i = 0; i < 4; ++i){
      int l  = i * 256 + tid;        // 16B-chunk index 0..1023
      int r  = l >> 3, c = (l & 7) * 8;
      const short* ga = Abf + (size_t)(bm + r) * K2 + aoff + c;
      const short* gb = Wbf + (size_t)(bn + r) * K2 + boff + c;
      short* la = As + ((i * 256 + w * 64) << 3);   // wave-uniform base
      short* lb = Bs + ((i * 256 + w * 64) << 3);
      __builtin_amdgcn_global_load_lds(
          (const __attribute__((address_space(1))) unsigned*)ga,
          (__attribute__((address_space(3))) unsigned*)la, 16, 0, 0);
      __builtin_amdgcn_global_load_lds(
          (const __attribute__((address_space(1))) unsigned*)gb,
          (__attribute__((address_space(3))) unsigned*)lb, 16, 0, 0);
    }
    __syncthreads();                 // drains vmcnt, tile ready
    #pragma unroll
    for (int ks = 0; ks < 2; ++ks){
      bf16x8 fa[4], fb[4];
      #pragma unroll
      for (int mi = 0; mi < 4; ++mi)
        fa[mi] = *(const bf16x8*)&As[(wr*64 + mi*16 + lrow) * 64 + ks*32 + lk];
      #pragma unroll
      for (int ni = 0; ni < 4; ++ni)
        fb[ni] = *(const bf16x8*)&Bs[(wc*64 + ni*16 + lrow) * 64 + ks*32 + lk];
      #pragma unroll
      for (int mi = 0; mi < 4; ++mi)
        #pragma unroll
        for (int ni = 0; ni < 4; ++ni)
          acc[mi][ni] = __builtin_amdgcn_mfma_f32_16x16x32_bf16(
              fa[mi], fb[ni], acc[mi][ni], 0, 0, 0);
    }
  }
  // epilogue: col = lane&15 (+n offsets), row = (lane>>4)*4 + j (+m offsets)
  #pragma unroll
  for (int mi = 0; mi < 4; ++mi){
    #pragma unroll
    for (int ni = 0; ni < 4; ++ni){
      int gn = bn + wc*64 + ni*16 + lrow;
      float bv = bias[gn];
      #pragma unroll
      for (int j = 0; j < 4; ++j){
        int gm = bm + wr*64 + mi*16 + (lane >> 4) * 4 + j;
        if (gm < NN)
          C[(size_t)gm * GOUT + gn] = acc[mi][ni][j] + bv;
      }
    }
  }
}

// ---------------------------------------------------------------------------
// h[n,d] = mesh[n,0:4] . embed_w[d,0:4] + embed_b[d]
// ---------------------------------------------------------------------------
__global__ void k_embed(const float* __restrict__ mesh,
                        const float* __restrict__ w, const float* __restrict__ b,
                        float* __restrict__ h)
{
  int i = blockIdx.x * blockDim.x + threadIdx.x;
  if (i >= NN * DTR) return;
  int n = i >> 6, d = i & 63;
  const float* mr = mesh + n * 4;
  const float* wr = w + d * 4;
  h[i] = fmaf(mr[0], wr[0], fmaf(mr[1], wr[1], fmaf(mr[2], wr[2], mr[3]*wr[3]))) + b[d];
}

// ---------------------------------------------------------------------------
// split-K flash attention, stage 1: partials per (query, ksplit)
// grid (CDIV(SEQ,128), BATCH*NHTR, KSPLIT), block 128
// qkv row layout (192 floats): [Q 0..63 | K 64..127 | V 128..191], head h at h*16
// ---------------------------------------------------------------------------
__global__ __launch_bounds__(128) void k_attn_part(const float* __restrict__ qkv,
    float* __restrict__ Pm, float* __restrict__ Pl, float* __restrict__ Pacc)
{
  __shared__ float Ks[128][DHD];
  __shared__ float Vs[128][DHD];
  const int q  = blockIdx.x * 128 + threadIdx.x;
  const int bh = blockIdx.y;
  const int b  = bh >> 2, h = bh & 3;
  const int ks = blockIdx.z;
  const bool valid = q < SEQ;
  float qv[DHD];
  if (valid){
    const float4* qr = (const float4*)(qkv + ((size_t)(b*SEQ + q))*192 + h*DHD);
    #pragma unroll
    for (int j = 0; j < 4; ++j){
      float4 t = qr[j];
      qv[j*4+0] = t.x; qv[j*4+1] = t.y; qv[j*4+2] = t.z; qv[j*4+3] = t.w;
    }
  }
  float m = -1e30f, l = 0.f, acc[DHD] = {};
  const int kbeg = ks * KCH, kend = kbeg + KCH;
  for (int kt = kbeg; kt < kend; kt += 128){
    int cnt = min(128, kend - kt);
    __syncthreads();
    for (int el = threadIdx.x; el < cnt * 4; el += 128){
      int r = el >> 2, d4 = el & 3;
      // base: float4* at float offset h*16 within the row
      const float4* base = (const float4*)(qkv + ((size_t)(b*SEQ + kt + r))*192 + h*DHD);
      ((float4*)Ks[r])[d4] = base[16 + d4];      // +64 floats  = K block
      ((float4*)Vs[r])[d4] = base[32 + d4];      // +128 floats = V block
    }
    __syncthreads();
    if (valid){
      for (int r = 0; r < cnt; ++r){
        float s = 0.f;
        #pragma unroll
        for (int d = 0; d < DHD; ++d) s = fmaf(qv[d], Ks[r][d], s);
        s *= 0.25f;
        float mn = fmaxf(m, s);
        float cc = __expf(m - mn), p = __expf(s - mn);
        l = l * cc + p;
        #pragma unroll
        for (int d = 0; d < DHD; ++d) acc[d] = fmaf(acc[d], cc, p * Vs[r][d]);
        m = mn;
      }
    }
  }
  if (valid){
    size_t qi = ((size_t)bh * SEQ + q) * KSPLIT + ks;
    Pm[qi] = m; Pl[qi] = l;
    #pragma unroll
    for (int d = 0; d < DHD; ++d) Pacc[qi*DHD + d] = acc[d];
  }
}

// stage 2: merge KSPLIT partials per query -> o[N][64]
__global__ void k_attn_comb(const float* __restrict__ Pm, const float* __restrict__ Pl,
                            const float* __restrict__ Pacc, float* __restrict__ o)
{
  int qi = blockIdx.x * blockDim.x + threadIdx.x;
  if (qi >= BATCH * NHTR * SEQ) return;
  float m = -1e30f;
  #pragma unroll
  for (int ks = 0; ks < KSPLIT; ++ks) m = fmaxf(m, Pm[(size_t)qi*KSPLIT + ks]);
  float l = 0.f, acc[DHD] = {};
  #pragma unroll
  for (int ks = 0; ks < KSPLIT; ++ks){
    size_t p = (size_t)qi*KSPLIT + ks;
    float sc = __expf(Pm[p] - m);
    l += Pl[p] * sc;
    #pragma unroll
    for (int d = 0; d < DHD; ++d) acc[d] = fmaf(Pacc[p*DHD + d], sc, acc[d]);
  }
  int bh = qi / SEQ, q = qi - bh * SEQ;
  int b = bh >> 2, h = bh & 3;
  float inv = 1.f / l;
  #pragma unroll
  for (int d = 0; d < DHD; ++d)
    o[((size_t)(b*SEQ + q))*64 + h*DHD + d] = acc[d] * inv;
}

// ---------------------------------------------------------------------------
__global__ __launch_bounds__(256) void k_addln(const float* __restrict__ x,
    const float* __restrict__ y, const float* __restrict__ g,
    const float* __restrict__ b, float* __restrict__ out)
{
  int row = blockIdx.x * 4 + (threadIdx.x >> 6);
  int lane = threadIdx.x & 63;
  if (row >= NN) return;
  float v = x[(size_t)row*64 + lane] + y[(size_t)row*64 + lane];
  float s1 = v, s2 = v * v;
  #pragma unroll
  for (int o = 32; o; o >>= 1){ s1 += __shfl_xor(s1, o); s2 += __shfl_xor(s2, o); }
  float mean = s1 * (1.f/64.f);
  float var  = s2 * (1.f/64.f) - mean * mean;
  float r = rsqrtf(var + 1e-5f);
  out[(size_t)row*64 + lane] = (v - mean) * r * g[lane] + b[lane];
}

__global__ void k_concat_feats(const float* __restrict__ x,
                               const float* __restrict__ tout,
                               float* __restrict__ feats)
{
  int i = blockIdx.x * blockDim.x + threadIdx.x;
  if (i >= NN * 21) return;
  int n = i / 21, c = i - 21*n;
  feats[i] = (c < 5) ? x[(size_t)n*7 + 2 + c] : tout[(size_t)n*16 + c - 5];
}

__global__ void k_initcoord(const float* __restrict__ x, float* __restrict__ coord)
{
  int i = blockIdx.x * blockDim.x + threadIdx.x;
  if (i >= NN * 2) return;
  coord[i] = x[(size_t)(i >> 1)*7 + (i & 1)];
}

// ---------------------------------------------------------------------------
// CSR build (by dst). dst for e>=NEDGE is the self-loop e-NEDGE.
// ---------------------------------------------------------------------------
__global__ void k_count(const int* __restrict__ dst, int* __restrict__ cnt)
{
  int e = blockIdx.x * blockDim.x + threadIdx.x;
  if (e >= ELOOP) return;
  int d = (e < NEDGE) ? dst[e] : e - NEDGE;
  atomicAdd(&cnt[d], 1);
}

__global__ __launch_bounds__(1024) void k_scan(const int* __restrict__ cnt,
                                               int* __restrict__ ptr)
{
  __shared__ int part[1024];
  int tid = threadIdx.x;
  const int per = 8;
  int loc[per]; int s = 0;
  int base = tid * per;
  #pragma unroll
  for (int i = 0; i < per; ++i){
    int v = (base + i < NN) ? cnt[base + i] : 0;
    loc[i] = s; s += v;
  }
  part[tid] = s;
  __syncthreads();
  for (int off = 1; off < 1024; off <<= 1){
    int v = 0;
    if (tid >= off) v = part[tid - off];
    __syncthreads();
    if (tid >= off) part[tid] += v;
    __syncthreads();
  }
  int pre = tid ? part[tid - 1] : 0;
  #pragma unroll
  for (int i = 0; i < per; ++i)
    if (base + i < NN) ptr[base + i] = pre + loc[i];
  if (tid == 1023) ptr[NN] = part[1023];
}

__global__ void k_fill(const int* __restrict__ dst, const int* __restrict__ ptr,
                       int* __restrict__ fil, int* __restrict__ eid)
{
  int e = blockIdx.x * blockDim.x + threadIdx.x;
  if (e >= ELOOP) return;
  int d = (e < NEDGE) ? dst[e] : e - NEDGE;
  int pos = ptr[d] + atomicAdd(&fil[d], 1);
  eid[pos] = e;
}

// ---------------------------------------------------------------------------
// logits[e,h] = sum_c lrelu(xl[src,h,c]+xr[dst,h,c]) * att[h,c]; wave/(e,h)
// float4 vector loads: 2 iterations x 64 lanes x 4 floats = 512 channels
// ---------------------------------------------------------------------------
__global__ __launch_bounds__(256) void k_logits(const float* __restrict__ xl,
    const float* __restrict__ xr, const int* __restrict__ src_a,
    const int* __restrict__ dst_a, const float* __restrict__ att,
    float* __restrict__ logits)
{
  int wid = blockIdx.x * 4 + (threadIdx.x >> 6);
  if (wid >= ELOOP * NHEADS) return;
  int e = wid / NHEADS, h = wid - NHEADS * e;
  int lane = threadIdx.x & 63;
  int s = (e < NEDGE) ? src_a[e] : e - NEDGE;
  int d = (e < NEDGE) ? dst_a[e] : e - NEDGE;
  const float4* pl = (const float4*)(xl + (size_t)s * GOUT + h * HCD);
  const float4* pr = (const float4*)(xr + (size_t)d * GOUT + h * HCD);
  const float4* pa = (const float4*)(att + h * HCD);
  float acc = 0.f;
  #pragma unroll
  for (int j = 0; j < 2; ++j){
    int c = j * 64 + lane;
    float4 a = pl[c], r = pr[c], w = pa[c];
    float v;
    v = a.x + r.x; v = v > 0.f ? v : 0.2f * v; acc = fmaf(v, w.x, acc);
    v = a.y + r.y; v = v > 0.f ? v : 0.2f * v; acc = fmaf(v, w.y, acc);
    v = a.z + r.z; v = v > 0.f ? v : 0.2f * v; acc = fmaf(v, w.z, acc);
    v = a.w + r.w; v = v > 0.f ? v : 0.2f * v; acc = fmaf(v, w.w, acc);
  }
  #pragma unroll
  for (int o = 32; o; o >>= 1) acc += __shfl_xor(acc, o);
  if (lane == 0) logits[wid] = acc;
}

__global__ void k_stats(const float* __restrict__ logits, const int* __restrict__ ptr,
                        const int* __restrict__ eid, float* __restrict__ mx,
                        float* __restrict__ inv)
{
  int i = blockIdx.x * blockDim.x + threadIdx.x;
  if (i >= NN * NHEADS) return;
  int n = i / NHEADS, h = i - NHEADS * n;
  int s0 = ptr[n], s1 = ptr[n + 1];
  float m = -1e30f;
  for (int t = s0; t < s1; ++t) m = fmaxf(m, logits[eid[t]*NHEADS + h]);
  float s = 0.f;
  for (int t = s0; t < s1; ++t) s += __expf(logits[eid[t]*NHEADS + h] - m);
  mx[i] = m; inv[i] = 1.f / s;
}

// ---------------------------------------------------------------------------
// hidden[n,c] = selu(mean_h sum_{e in(n)} a[e,h]*xl[src,h,c] + gbias[c])
// ---------------------------------------------------------------------------
__global__ __launch_bounds__(256) void k_agg(const float* __restrict__ xl,
    const float* __restrict__ logits, const float* __restrict__ mx,
    const float* __restrict__ inv, const int* __restrict__ ptr,
    const int* __restrict__ eid, const int* __restrict__ src_a,
    const float* __restrict__ gbias, float* __restrict__ hidden)
{
  const int n = blockIdx.x;
  const int tid = threadIdx.x;
  __shared__ float a_sh[64 * NHEADS];
  __shared__ int src_sh[64];
  const int s0 = ptr[n];
  const int deg = ptr[n + 1] - s0;
  float acc[12] = {};
  for (int base = 0; base < deg; base += 64){
    int cnt = min(64, deg - base);
    __syncthreads();
    for (int t = tid; t < cnt * NHEADS; t += 256){
      int ei = t / NHEADS, h = t - NHEADS * ei;
      int e = eid[s0 + base + ei];
      a_sh[t] = __expf(logits[e*NHEADS + h] - mx[n*NHEADS + h]) * inv[n*NHEADS + h];
      if (h == 0) src_sh[ei] = (e < NEDGE) ? src_a[e] : e - NEDGE;
    }
    __syncthreads();
    for (int i2 = 0; i2 < cnt; ++i2){
      const float* row = xl + (size_t)src_sh[i2] * GOUT;
      #pragma unroll
      for (int k = 0; k < 12; ++k){
        int slot = tid + (k << 8);
        acc[k] = fmaf(row[slot], a_sh[i2*NHEADS + (slot >> 9)], acc[k]);
      }
    }
  }
  float m1 = (acc[0]+acc[2]+acc[4]+acc[6]+acc[8]+acc[10]) * (1.f/6.f);
  float m2 = (acc[1]+acc[3]+acc[5]+acc[7]+acc[9]+acc[11]) * (1.f/6.f);
  hidden[(size_t)n*HIDD + tid]       = selu_f(m1 + gbias[tid]);
  hidden[(size_t)n*HIDD + 256 + tid] = selu_f(m2 + gbias[256 + tid]);
}

// ---------------------------------------------------------------------------
extern "C" void kernel_launch(void* const* d_in, const int* in_sizes, int n_in,
                              void* d_out, int out_size, void* d_ws, size_t ws_size,
                              hipStream_t stream)
{
  const float* mesh     = (const float*)d_in[1];
  const float* xin      = (const float*)d_in[2];
  const int*   ei       = (const int*)d_in[3];
  const float* embed_w  = (const float*)d_in[4];
  const float* embed_b  = (const float*)d_in[5];
  const float* in_proj_w= (const float*)d_in[6];
  const float* in_proj_b= (const float*)d_in[7];
  const float* out_proj_w=(const float*)d_in[8];
  const float* out_proj_b=(const float*)d_in[9];
  const float* ln1_g    = (const float*)d_in[10];
  const float* ln1_b    = (const float*)d_in[11];
  const float* ln2_g    = (const float*)d_in[12];
  const float* ln2_b    = (const float*)d_in[13];
  const float* ff1_w    = (const float*)d_in[14];
  const float* ff1_b    = (const float*)d_in[15];
  const float* ff2_w    = (const float*)d_in[16];
  const float* ff2_b    = (const float*)d_in[17];
  const float* tout_w   = (const float*)d_in[18];
  const float* tout_b   = (const float*)d_in[19];
  const float* lin_w    = (const float*)d_in[20];
  const float* lin_b    = (const float*)d_in[21];
  const float* gat_wl   = (const float*)d_in[22];
  const float* gat_bl   = (const float*)d_in[23];
  const float* gat_wr   = (const float*)d_in[24];
  const float* gat_br   = (const float*)d_in[25];
  const float* gat_att  = (const float*)d_in[26];
  const float* gat_bias = (const float*)d_in[27];
  const float* coord1_w = (const float*)d_in[28];
  const float* coord1_b = (const float*)d_in[29];
  const float* coord2_w = (const float*)d_in[30];
  const float* coord2_b = (const float*)d_in[31];

  const int* esrc = ei;
  const int* edst = ei + NEDGE;

  char* ws = (char*)d_ws;
  size_t off = 0;
  auto alloc = [&](size_t nbytes){
    size_t o = off; off += (nbytes + 255) & ~(size_t)255; return o;
  };
  float* hidden = (float*)(ws + alloc((size_t)NN * HIDD * 4));
  float* coord  = (float*)(ws + alloc((size_t)NN * 2 * 4));
  float* xl     = (float*)(ws + alloc((size_t)NN * GOUT * 4));
  float* xr     = (float*)(ws + alloc((size_t)NN * GOUT * 4));
  float* logits = (float*)(ws + alloc((size_t)ELOOP * NHEADS * 4));
  float* mxb    = (float*)(ws + alloc((size_t)NN * NHEADS * 4));
  float* invb   = (float*)(ws + alloc((size_t)NN * NHEADS * 4));
  float* c1     = (float*)(ws + alloc((size_t)NN * 256 * 4));
  int*   ptr    = (int*)(ws + alloc((size_t)(NN + 1) * 4));
  int*   eid    = (int*)(ws + alloc((size_t)ELOOP * 4));
  int*   cnt    = (int*)(ws + alloc((size_t)NN * 4));
  int*   fil    = (int*)(ws + alloc((size_t)NN * 4));
  short* abf    = (short*)(ws + alloc((size_t)MPAD * K2 * 2));
  short* wlbf   = (short*)(ws + alloc((size_t)GOUT * K2 * 2));
  short* wrbf   = (short*)(ws + alloc((size_t)GOUT * K2 * 2));

  // phase-A temporaries aliased inside xl / xr (free before GAT loop)
  float* h     = (float*)((char*)xl + 0);
  float* qkv   = (float*)((char*)xl + (4u << 20));
  float* o     = (float*)((char*)xl + (12u << 20));
  float* tmp   = (float*)((char*)xl + (16u << 20));
  float* feats = (float*)((char*)xl + (20u << 20));
  float* toutb = (float*)((char*)xl + (24u << 20));
  float* ffmid = xr;
  float* Pm    = (float*)((char*)xr + (70u << 20));   // 32000*8 floats = 1 MB
  float* Pl    = (float*)((char*)xr + (72u << 20));
  float* Pacc  = (float*)((char*)xr + (74u << 20));   // 32000*8*16 = 16.4 MB

  // ---- transformer ----
  k_embed<<<CDIV(NN*DTR, 256), 256, 0, stream>>>(mesh, embed_w, embed_b, h);
  k_gemm<0><<<dim3(CDIV(192,64), CDIV(NN,64)), 256, 0, stream>>>(h, in_proj_w, in_proj_b, qkv, NN, 192, DTR);
  k_attn_part<<<dim3(CDIV(SEQ,128), BATCH*NHTR, KSPLIT), 128, 0, stream>>>(qkv, Pm, Pl, Pacc);
  k_attn_comb<<<CDIV(BATCH*NHTR*SEQ, 256), 256, 0, stream>>>(Pm, Pl, Pacc, o);
  k_gemm<0><<<dim3(1, CDIV(NN,64)), 256, 0, stream>>>(o, out_proj_w, out_proj_b, tmp, NN, DTR, DTR);
  k_addln<<<CDIV(NN,4), 256, 0, stream>>>(h, tmp, ln1_g, ln1_b, h);
  k_gemm<1><<<dim3(CDIV(FFD,64), CDIV(NN,64)), 256, 0, stream>>>(h, ff1_w, ff1_b, ffmid, NN, FFD, DTR);
  k_gemm<0><<<dim3(1, CDIV(NN,64)), 256, 0, stream>>>(ffmid, ff2_w, ff2_b, tmp, NN, DTR, FFD);
  k_addln<<<CDIV(NN,4), 256, 0, stream>>>(h, tmp, ln2_g, ln2_b, h);
  k_gemm<0><<<dim3(1, CDIV(NN,64)), 256, 0, stream>>>(h, tout_w, tout_b, toutb, NN, TOUTD, DTR);
  k_concat_feats<<<CDIV(NN*21, 256), 256, 0, stream>>>(xin, toutb, feats);
  k_gemm<2><<<dim3(CDIV(HIDD,64), CDIV(NN,64)), 256, 0, stream>>>(feats, lin_w, lin_b, hidden, NN, HIDD, 21);
  k_initcoord<<<CDIV(NN*2, 256), 256, 0, stream>>>(xin, coord);

  // ---- CSR by dst + weight conversion (once) ----
  hipMemsetAsync(cnt, 0, (size_t)NN * 4, stream);
  hipMemsetAsync(fil, 0, (size_t)NN * 4, stream);
  k_count<<<CDIV(ELOOP, 256), 256, 0, stream>>>(edst, cnt);
  k_scan<<<1, 1024, 0, stream>>>(cnt, ptr);
  k_fill<<<CDIV(ELOOP, 256), 256, 0, stream>>>(edst, ptr, fil, eid);
  k_cvt_w<<<CDIV(GOUT*K1, 256), 256, 0, stream>>>(gat_wl, wlbf);
  k_cvt_w<<<CDIV(GOUT*K1, 256), 256, 0, stream>>>(gat_wr, wrbf);

  // ---- GAT loops ----
  for (int it = 0; it < 3; ++it){
    k_cvt_a<<<CDIV(MPAD*K1, 256), 256, 0, stream>>>(coord, hidden, abf);
    k_gat_mfma<<<dim3(GOUT/128, MPAD/128), 256, 0, stream>>>(abf, wlbf, gat_bl, xl);
    k_gat_mfma<<<dim3(GOUT/128, MPAD/128), 256, 0, stream>>>(abf, wrbf, gat_br, xr);
    k_logits<<<CDIV(ELOOP*NHEADS, 4), 256, 0, stream>>>(xl, xr, esrc, edst, gat_att, logits);
    k_stats<<<CDIV(NN*NHEADS, 256), 256, 0, stream>>>(logits, ptr, eid, mxb, invb);
    k_agg<<<NN, 256, 0, stream>>>(xl, logits, mxb, invb, ptr, eid, esrc, gat_bias, hidden);
    k_gemm<2><<<dim3(CDIV(256,64), CDIV(NN,64)), 256, 0, stream>>>(hidden, coord1_w, coord1_b, c1, NN, 256, HIDD);
    float* cdst = (it == 2) ? (float*)d_out : coord;
    k_gemm<0><<<dim3(1, CDIV(NN,64)), 256, 0, stream>>>(c1, coord2_w, coord2_b, cdst, NN, 2, 256);
  }
}